// Round 2
// baseline (39984.531 us; speedup 1.0000x reference)
//
#include <hip/hip_runtime.h>
#include <hip/hip_cooperative_groups.h>

namespace cg = cooperative_groups;

#define H_DIM   2048
#define N_HALF  1024
#define B_SZ    128
#define T_STEPS 512
#define IN_DIM  64
#define ALPHA_F 0.05f
#define OMA_F   0.95f   // 1 - ALPHA

typedef __bf16 bf16x8 __attribute__((ext_vector_type(8)));
typedef float  f32x4  __attribute__((ext_vector_type(4)));

// round-to-nearest-even f32 -> bf16 bits
__device__ __forceinline__ unsigned short f2bf(float f) {
    union { float f; unsigned int u; } v; v.f = f;
    unsigned int u = v.u;
    u += 0x7FFFu + ((u >> 16) & 1u);
    return (unsigned short)(u >> 16);
}

// ---------------------------------------------------------------------------
// Wt[j][k] = bf16(W[k][j])  (transpose + convert, LDS-tiled 64x64)
// ---------------------------------------------------------------------------
__global__ void wt_kernel(const float* __restrict__ W, unsigned short* __restrict__ Wt) {
    __shared__ float tile[64][65];
    const int jb = blockIdx.x * 64;
    const int kb = blockIdx.y * 64;
    const int tx = threadIdx.x;   // 0..63
    const int ty = threadIdx.y;   // 0..3
    #pragma unroll
    for (int r = ty; r < 64; r += 4)
        tile[r][tx] = W[(size_t)(kb + r) * H_DIM + jb + tx];
    __syncthreads();
    #pragma unroll
    for (int r = ty; r < 64; r += 4)
        Wt[(size_t)(jb + r) * H_DIM + kb + tx] = f2bf(tile[tx][r]);
}

// ---------------------------------------------------------------------------
__global__ void vel_kernel(const float* __restrict__ x, const float* __restrict__ w_in,
                           float* __restrict__ vel) {
    const int tb = blockIdx.x * blockDim.x + threadIdx.x;
    if (tb >= T_STEPS * B_SZ) return;
    const float* xp = x + (size_t)tb * IN_DIM;
    float s = 0.f;
    #pragma unroll
    for (int i = 0; i < IN_DIM; i += 4) {
        float4 xv = *reinterpret_cast<const float4*>(xp + i);
        float4 wv = *reinterpret_cast<const float4*>(w_in + i);
        s += xv.x * wv.x + xv.y * wv.y + xv.z * wv.z + xv.w * wv.w;
    }
    vel[tb] = s;
}

// ---------------------------------------------------------------------------
__global__ void hbf_init_kernel(const float* __restrict__ h0, unsigned short* __restrict__ hbf) {
    const int i = blockIdx.x * blockDim.x + threadIdx.x;
    hbf[i] = f2bf(h0[i]);
}

// ---------------------------------------------------------------------------
// Persistent cooperative kernel: all 512 steps in one launch.
// 256 blocks (1/CU) x 256 threads (4 waves). Block tile: 32 batch-rows x 32 cols.
// Wave quadrant: 16x16, full K=2048 as 4 independent accumulator chains.
// B (Wt slice, 32 cols x 2048 K bf16 = 128 KB) lives in LDS for ALL steps,
// stored in exact MFMA-fragment order -> every B read is a conflict-free
// full-wave ds_read_b128 of a contiguous 1 KB block.
// ---------------------------------------------------------------------------
__global__ __launch_bounds__(256, 1) void ring_coop_kernel(
        const unsigned short* __restrict__ Wt,
        unsigned short* __restrict__ hbf0,
        unsigned short* __restrict__ hbf1,
        const float* __restrict__ vel,
        const float* __restrict__ hidden0,
        float* __restrict__ acts,
        float* __restrict__ outT) {
    __shared__ __align__(16) unsigned char ldsB[131072];  // [ch][ks][q][col][16B]

    const int tid = threadIdx.x;
    const int bid = blockIdx.x;
    const int colg = bid & 63;          // 64 col-groups of 32
    const int rowg = bid >> 6;          // 4 row-groups of 32
    const int colbase = colg * 32;
    const int rowbase = rowg * 32;

    // ---- one-time: stage B slice into LDS in fragment order ----
    for (int c = tid; c < 8192; c += 256) {
        const int col = c & 15;
        const int q   = (c >> 4) & 3;
        const int ks  = (c >> 6) & 63;
        const int ch  = (c >> 12) & 1;
        const size_t src = (size_t)(colbase + ch * 16 + col) * H_DIM + ks * 32 + q * 8;
        *reinterpret_cast<uint4*>(ldsB + (size_t)c * 16) =
            *reinterpret_cast<const uint4*>(Wt + src);
    }
    __syncthreads();

    const int lane = tid & 63;
    const int w    = tid >> 6;              // 0..3
    const int rowhalf = w >> 1, colhalf = w & 1;
    const int wrow = rowbase + rowhalf * 16;
    const int wcol = colbase + colhalf * 16;
    const int r16  = lane & 15;
    const int q4   = lane >> 4;

    const unsigned char* Bp = ldsB + colhalf * 65536 + q4 * 256 + r16 * 16;
    const int j = wcol + r16;
    const float gamma = (j < N_HALF) ? -1.0f : 1.0f;
    const int brow0 = wrow + q4 * 4;

    cg::grid_group grid = cg::this_grid();

    for (int t = 0; t < T_STEPS; ++t) {
        const unsigned short* hin  = (t & 1) ? hbf1 : hbf0;
        unsigned short*       hout = (t & 1) ? hbf0 : hbf1;
        const float* hprev = t ? (acts + (size_t)(t - 1) * B_SZ * H_DIM) : hidden0;
        float*       acts_t = acts + (size_t)t * B_SZ * H_DIM;
        const float* vel_t  = vel + (size_t)t * B_SZ;

        const bf16x8* Ap = reinterpret_cast<const bf16x8*>(
            hin + (size_t)(wrow + r16) * H_DIM + q4 * 8);

        f32x4 acc0 = {0.f,0.f,0.f,0.f}, acc1 = {0.f,0.f,0.f,0.f};
        f32x4 acc2 = {0.f,0.f,0.f,0.f}, acc3 = {0.f,0.f,0.f,0.f};
        #pragma unroll 4
        for (int s = 0; s < 16; ++s) {
            bf16x8 a0 = Ap[s * 4];
            bf16x8 a1 = Ap[s * 4 + 64];
            bf16x8 a2 = Ap[s * 4 + 128];
            bf16x8 a3 = Ap[s * 4 + 192];
            bf16x8 b0 = *reinterpret_cast<const bf16x8*>(Bp + (size_t)(s)      * 1024);
            bf16x8 b1 = *reinterpret_cast<const bf16x8*>(Bp + (size_t)(s + 16) * 1024);
            bf16x8 b2 = *reinterpret_cast<const bf16x8*>(Bp + (size_t)(s + 32) * 1024);
            bf16x8 b3 = *reinterpret_cast<const bf16x8*>(Bp + (size_t)(s + 48) * 1024);
            acc0 = __builtin_amdgcn_mfma_f32_16x16x32_bf16(a0, b0, acc0, 0, 0, 0);
            acc1 = __builtin_amdgcn_mfma_f32_16x16x32_bf16(a1, b1, acc1, 0, 0, 0);
            acc2 = __builtin_amdgcn_mfma_f32_16x16x32_bf16(a2, b2, acc2, 0, 0, 0);
            acc3 = __builtin_amdgcn_mfma_f32_16x16x32_bf16(a3, b3, acc3, 0, 0, 0);
        }
        f32x4 h2h = (acc0 + acc1) + (acc2 + acc3);

        #pragma unroll
        for (int i = 0; i < 4; ++i) {
            const int b = brow0 + i;
            const float v  = vel_t[b];
            const float hp = hprev[(size_t)b * H_DIM + j];
            const float pre = fmaf(v, gamma, 1.0f) + h2h[i];
            const float hn = OMA_F * hp + ALPHA_F * fmaxf(pre, 0.0f);
            acts_t[(size_t)b * H_DIM + j] = hn;
            hout[(size_t)b * H_DIM + j] = f2bf(hn);
            if (t == T_STEPS - 1) outT[(size_t)b * H_DIM + j] = hn;
        }

        __threadfence();   // device-scope release for cross-XCD visibility
        grid.sync();
        __threadfence();   // acquire side
    }
}

// ---------------------------------------------------------------------------
// Fallback per-step kernel (round-1 proven path) if cooperative launch fails.
// ---------------------------------------------------------------------------
__global__ __launch_bounds__(256) void step_kernel(
        const unsigned short* __restrict__ Wt,
        const unsigned short* __restrict__ hbf_in,
        unsigned short* __restrict__ hbf_out,
        const float* __restrict__ vel_t,
        const float* __restrict__ hprev,
        float* __restrict__ acts_t,
        float* __restrict__ outT) {
    const int lane = threadIdx.x & 63;
    const int w    = threadIdx.x >> 6;
    const int bid  = blockIdx.x;
    const int mg   = bid >> 7;
    const int n    = bid & 127;
    const int base_b = mg * 64 + w * 16;
    const int base_j = n * 16;
    const int r16  = lane & 15;
    const int koff = (lane >> 4) * 8;

    const bf16x8* Ap = reinterpret_cast<const bf16x8*>(
        hbf_in + (size_t)(base_b + r16) * H_DIM + koff);
    const bf16x8* Bp = reinterpret_cast<const bf16x8*>(
        Wt + (size_t)(base_j + r16) * H_DIM + koff);

    f32x4 acc0 = {0.f, 0.f, 0.f, 0.f};
    f32x4 acc1 = {0.f, 0.f, 0.f, 0.f};
    #pragma unroll 4
    for (int kk = 0; kk < 32; ++kk) {
        bf16x8 a0 = Ap[kk * 4];
        bf16x8 b0 = Bp[kk * 4];
        bf16x8 a1 = Ap[kk * 4 + 128];
        bf16x8 b1 = Bp[kk * 4 + 128];
        acc0 = __builtin_amdgcn_mfma_f32_16x16x32_bf16(a0, b0, acc0, 0, 0, 0);
        acc1 = __builtin_amdgcn_mfma_f32_16x16x32_bf16(a1, b1, acc1, 0, 0, 0);
    }
    f32x4 h2h = acc0 + acc1;

    const int j = base_j + r16;
    const float gamma = (j < N_HALF) ? -1.0f : 1.0f;
    const int brow0 = base_b + (lane >> 4) * 4;
    #pragma unroll
    for (int i = 0; i < 4; ++i) {
        const int b = brow0 + i;
        const float v  = vel_t[b];
        const float hp = hprev[(size_t)b * H_DIM + j];
        const float pre = fmaf(v, gamma, 1.0f) + h2h[i];
        const float hn = OMA_F * hp + ALPHA_F * fmaxf(pre, 0.0f);
        acts_t[(size_t)b * H_DIM + j] = hn;
        hbf_out[(size_t)b * H_DIM + j] = f2bf(hn);
        if (outT) outT[(size_t)b * H_DIM + j] = hn;
    }
}

// ---------------------------------------------------------------------------
extern "C" void kernel_launch(void* const* d_in, const int* in_sizes, int n_in,
                              void* d_out, int out_size, void* d_ws, size_t ws_size,
                              hipStream_t stream) {
    const float* x       = (const float*)d_in[0];  // [T,B,IN]
    const float* hidden0 = (const float*)d_in[1];  // [B,H]
    const float* w_attr  = (const float*)d_in[2];  // [H,H]
    const float* w_in    = (const float*)d_in[3];  // [1,IN]

    float* acts = (float*)d_out;                               // [T,B,H]
    float* outT = acts + (size_t)T_STEPS * B_SZ * H_DIM;       // [B,H]

    unsigned char* ws = (unsigned char*)d_ws;
    unsigned short* Wt   = (unsigned short*)ws;                             // 8 MB
    unsigned short* hbf0 = (unsigned short*)(ws + ((size_t)8 << 20));       // 512 KB
    unsigned short* hbf1 = hbf0 + (size_t)B_SZ * H_DIM;                     // 512 KB
    float* vel = (float*)(ws + ((size_t)8 << 20) + (size_t)2 * B_SZ * H_DIM * 2); // 256 KB

    wt_kernel<<<dim3(32, 32), dim3(64, 4), 0, stream>>>(w_attr, Wt);
    vel_kernel<<<(T_STEPS * B_SZ + 255) / 256, 256, 0, stream>>>(x, w_in, vel);
    hbf_init_kernel<<<(B_SZ * H_DIM + 255) / 256, 256, 0, stream>>>(hidden0, hbf0);

    void* args[] = {(void*)&Wt, (void*)&hbf0, (void*)&hbf1, (void*)&vel,
                    (void*)&hidden0, (void*)&acts, (void*)&outT};
    hipError_t rc = hipLaunchCooperativeKernel(
        reinterpret_cast<void*>(ring_coop_kernel),
        dim3(256), dim3(256), args, 0, stream);

    if (rc != hipSuccess) {
        // fallback: per-step launches (round-1 path)
        for (int t = 0; t < T_STEPS; ++t) {
            const unsigned short* hin = (t & 1) ? hbf1 : hbf0;
            unsigned short* hout      = (t & 1) ? hbf0 : hbf1;
            const float* hprev = (t == 0) ? hidden0 : acts + (size_t)(t - 1) * B_SZ * H_DIM;
            step_kernel<<<256, 256, 0, stream>>>(
                Wt, hin, hout, vel + (size_t)t * B_SZ, hprev,
                acts + (size_t)t * B_SZ * H_DIM,
                (t == T_STEPS - 1) ? outT : nullptr);
        }
    }
}

// Round 3
// 26055.222 us; speedup vs baseline: 1.5346x; 1.5346x over previous
//
#include <hip/hip_runtime.h>

#define H_DIM   2048
#define N_HALF  1024
#define B_SZ    128
#define T_STEPS 512
#define IN_DIM  64
#define ALPHA_F 0.05f
#define OMA_F   0.95f   // 1 - ALPHA

typedef __bf16 bf16x8 __attribute__((ext_vector_type(8)));
typedef float  f32x4  __attribute__((ext_vector_type(4)));

// round-to-nearest-even f32 -> bf16 bits
__device__ __forceinline__ unsigned short f2bf(float f) {
    union { float f; unsigned int u; } v; v.f = f;
    unsigned int u = v.u;
    u += 0x7FFFu + ((u >> 16) & 1u);
    return (unsigned short)(u >> 16);
}

// ---------------------------------------------------------------------------
// Wt[j][k] = bf16(W[k][j])  (transpose + convert, LDS-tiled 64x64)
// ---------------------------------------------------------------------------
__global__ void wt_kernel(const float* __restrict__ W, unsigned short* __restrict__ Wt) {
    __shared__ float tile[64][65];
    const int jb = blockIdx.x * 64;
    const int kb = blockIdx.y * 64;
    const int tx = threadIdx.x;   // 0..63
    const int ty = threadIdx.y;   // 0..3
    #pragma unroll
    for (int r = ty; r < 64; r += 4)
        tile[r][tx] = W[(size_t)(kb + r) * H_DIM + jb + tx];
    __syncthreads();
    #pragma unroll
    for (int r = ty; r < 64; r += 4)
        Wt[(size_t)(jb + r) * H_DIM + kb + tx] = f2bf(tile[tx][r]);
}

// ---------------------------------------------------------------------------
__global__ void vel_kernel(const float* __restrict__ x, const float* __restrict__ w_in,
                           float* __restrict__ vel) {
    const int tb = blockIdx.x * blockDim.x + threadIdx.x;
    if (tb >= T_STEPS * B_SZ) return;
    const float* xp = x + (size_t)tb * IN_DIM;
    float s = 0.f;
    #pragma unroll
    for (int i = 0; i < IN_DIM; i += 4) {
        float4 xv = *reinterpret_cast<const float4*>(xp + i);
        float4 wv = *reinterpret_cast<const float4*>(w_in + i);
        s += xv.x * wv.x + xv.y * wv.y + xv.z * wv.z + xv.w * wv.w;
    }
    vel[tb] = s;
}

// ---------------------------------------------------------------------------
__global__ void hbf_init_kernel(const float* __restrict__ h0, unsigned short* __restrict__ hbf) {
    const int i = blockIdx.x * blockDim.x + threadIdx.x;
    hbf[i] = f2bf(h0[i]);
}

// ---------------------------------------------------------------------------
// Fast two-level grid barrier (256 blocks = 16 groups x 16).
// Monotone counters (memset to 0 per launch -> deterministic).
// bar[g*32]      : group-g arrival counter  (128 B apart)
// bar[16*32]     : root arrival counter
// bar[16*32+32]  : generation word (= steps completed)
// ---------------------------------------------------------------------------
__device__ __forceinline__ void ring_barrier(unsigned* bar, int t, int bid, int tid) {
    __threadfence();            // release: vmcnt drain + L2 writeback (per thread)
    __syncthreads();            // whole block's stores are now globally visible
    if (tid == 0) {
        unsigned* gcnt = bar + (bid >> 4) * 32;
        unsigned* rcnt = bar + 16 * 32;
        unsigned* gen  = bar + 16 * 32 + 32;
        unsigned old = __hip_atomic_fetch_add(gcnt, 1u, __ATOMIC_RELAXED,
                                              __HIP_MEMORY_SCOPE_AGENT);
        if (old == (unsigned)(t * 16 + 15)) {                 // last block of group
            unsigned r = __hip_atomic_fetch_add(rcnt, 1u, __ATOMIC_RELAXED,
                                                __HIP_MEMORY_SCOPE_AGENT);
            if (r == (unsigned)(t * 16 + 15)) {               // last group
                __hip_atomic_store(gen, (unsigned)(t + 1), __ATOMIC_RELAXED,
                                   __HIP_MEMORY_SCOPE_AGENT);
            }
        }
        while (__hip_atomic_load(gen, __ATOMIC_RELAXED, __HIP_MEMORY_SCOPE_AGENT)
               < (unsigned)(t + 1)) {
            __builtin_amdgcn_s_sleep(2);
        }
    }
    __syncthreads();
    __threadfence();            // acquire: invalidate L1/L2 before reading peers' data
}

// ---------------------------------------------------------------------------
// Persistent kernel: all 512 steps in one launch, custom barrier.
// 256 blocks (1/CU) x 256 threads (4 waves). Block tile: 32 rows x 32 cols.
// B (Wt slice, 32 cols x K=2048 bf16 = 128 KB) lives in LDS for ALL steps in
// MFMA-fragment order (conflict-free full-wave ds_read_b128).
// h_prev (f32) lives in registers: each thread reuses the 4 values it wrote.
// Only the bf16 h state (512 KB/step) crosses blocks, via plain stores/loads
// bracketed by the barrier's threadfences.
// ---------------------------------------------------------------------------
__global__ __launch_bounds__(256, 1) void ring_coop_kernel(
        const unsigned short* __restrict__ Wt,
        unsigned short* __restrict__ hbf0,
        unsigned short* __restrict__ hbf1,
        const float* __restrict__ vel,
        const float* __restrict__ hidden0,
        float* __restrict__ acts,
        float* __restrict__ outT,
        unsigned* __restrict__ bar) {
    __shared__ __align__(16) unsigned char ldsB[131072];  // [ch][ks][q][col][16B]

    const int tid = threadIdx.x;
    const int bid = blockIdx.x;
    const int colg = bid & 63;          // 64 col-groups of 32
    const int rowg = bid >> 6;          // 4 row-groups of 32
    const int colbase = colg * 32;
    const int rowbase = rowg * 32;

    // ---- one-time: stage B slice into LDS in fragment order ----
    for (int c = tid; c < 8192; c += 256) {
        const int col = c & 15;
        const int q   = (c >> 4) & 3;
        const int ks  = (c >> 6) & 63;
        const int ch  = (c >> 12) & 1;
        const size_t src = (size_t)(colbase + ch * 16 + col) * H_DIM + ks * 32 + q * 8;
        *reinterpret_cast<uint4*>(ldsB + (size_t)c * 16) =
            *reinterpret_cast<const uint4*>(Wt + src);
    }
    __syncthreads();

    const int lane = tid & 63;
    const int w    = tid >> 6;              // 0..3
    const int rowhalf = w >> 1, colhalf = w & 1;
    const int wrow = rowbase + rowhalf * 16;
    const int wcol = colbase + colhalf * 16;
    const int r16  = lane & 15;
    const int q4   = lane >> 4;

    const unsigned char* Bp = ldsB + colhalf * 65536 + q4 * 256 + r16 * 16;
    const int j = wcol + r16;
    const float gamma = (j < N_HALF) ? -1.0f : 1.0f;
    const int brow0 = wrow + q4 * 4;

    // h_prev in registers: this thread owns (brow0..brow0+3, j)
    f32x4 hreg;
    #pragma unroll
    for (int i = 0; i < 4; ++i)
        hreg[i] = hidden0[(size_t)(brow0 + i) * H_DIM + j];

    for (int t = 0; t < T_STEPS; ++t) {
        const unsigned short* hin  = (t & 1) ? hbf1 : hbf0;
        unsigned short*       hout = (t & 1) ? hbf0 : hbf1;
        float*       acts_t = acts + (size_t)t * B_SZ * H_DIM;
        const float* vel_t  = vel + (size_t)t * B_SZ;

        const bf16x8* Ap = reinterpret_cast<const bf16x8*>(
            hin + (size_t)(wrow + r16) * H_DIM + q4 * 8);

        f32x4 acc0 = {0.f,0.f,0.f,0.f}, acc1 = {0.f,0.f,0.f,0.f};
        f32x4 acc2 = {0.f,0.f,0.f,0.f}, acc3 = {0.f,0.f,0.f,0.f};
        #pragma unroll 8
        for (int s = 0; s < 16; ++s) {
            bf16x8 a0 = Ap[s * 4];
            bf16x8 a1 = Ap[s * 4 + 64];
            bf16x8 a2 = Ap[s * 4 + 128];
            bf16x8 a3 = Ap[s * 4 + 192];
            bf16x8 b0 = *reinterpret_cast<const bf16x8*>(Bp + (size_t)(s)      * 1024);
            bf16x8 b1 = *reinterpret_cast<const bf16x8*>(Bp + (size_t)(s + 16) * 1024);
            bf16x8 b2 = *reinterpret_cast<const bf16x8*>(Bp + (size_t)(s + 32) * 1024);
            bf16x8 b3 = *reinterpret_cast<const bf16x8*>(Bp + (size_t)(s + 48) * 1024);
            acc0 = __builtin_amdgcn_mfma_f32_16x16x32_bf16(a0, b0, acc0, 0, 0, 0);
            acc1 = __builtin_amdgcn_mfma_f32_16x16x32_bf16(a1, b1, acc1, 0, 0, 0);
            acc2 = __builtin_amdgcn_mfma_f32_16x16x32_bf16(a2, b2, acc2, 0, 0, 0);
            acc3 = __builtin_amdgcn_mfma_f32_16x16x32_bf16(a3, b3, acc3, 0, 0, 0);
        }
        f32x4 h2h = (acc0 + acc1) + (acc2 + acc3);

        #pragma unroll
        for (int i = 0; i < 4; ++i) {
            const int b = brow0 + i;
            const float v  = vel_t[b];
            const float pre = fmaf(v, gamma, 1.0f) + h2h[i];
            const float hn = OMA_F * hreg[i] + ALPHA_F * fmaxf(pre, 0.0f);
            hreg[i] = hn;
            acts_t[(size_t)b * H_DIM + j] = hn;
            hout[(size_t)b * H_DIM + j] = f2bf(hn);
            if (t == T_STEPS - 1) outT[(size_t)b * H_DIM + j] = hn;
        }

        ring_barrier(bar, t, bid, tid);
    }
}

// ---------------------------------------------------------------------------
// Fallback per-step kernel (round-1 proven path) if cooperative launch fails.
// ---------------------------------------------------------------------------
__global__ __launch_bounds__(256) void step_kernel(
        const unsigned short* __restrict__ Wt,
        const unsigned short* __restrict__ hbf_in,
        unsigned short* __restrict__ hbf_out,
        const float* __restrict__ vel_t,
        const float* __restrict__ hprev,
        float* __restrict__ acts_t,
        float* __restrict__ outT) {
    const int lane = threadIdx.x & 63;
    const int w    = threadIdx.x >> 6;
    const int bid  = blockIdx.x;
    const int mg   = bid >> 7;
    const int n    = bid & 127;
    const int base_b = mg * 64 + w * 16;
    const int base_j = n * 16;
    const int r16  = lane & 15;
    const int koff = (lane >> 4) * 8;

    const bf16x8* Ap = reinterpret_cast<const bf16x8*>(
        hbf_in + (size_t)(base_b + r16) * H_DIM + koff);
    const bf16x8* Bp = reinterpret_cast<const bf16x8*>(
        Wt + (size_t)(base_j + r16) * H_DIM + koff);

    f32x4 acc0 = {0.f, 0.f, 0.f, 0.f};
    f32x4 acc1 = {0.f, 0.f, 0.f, 0.f};
    #pragma unroll 4
    for (int kk = 0; kk < 32; ++kk) {
        bf16x8 a0 = Ap[kk * 4];
        bf16x8 b0 = Bp[kk * 4];
        bf16x8 a1 = Ap[kk * 4 + 128];
        bf16x8 b1 = Bp[kk * 4 + 128];
        acc0 = __builtin_amdgcn_mfma_f32_16x16x32_bf16(a0, b0, acc0, 0, 0, 0);
        acc1 = __builtin_amdgcn_mfma_f32_16x16x32_bf16(a1, b1, acc1, 0, 0, 0);
    }
    f32x4 h2h = acc0 + acc1;

    const int j = base_j + r16;
    const float gamma = (j < N_HALF) ? -1.0f : 1.0f;
    const int brow0 = base_b + (lane >> 4) * 4;
    #pragma unroll
    for (int i = 0; i < 4; ++i) {
        const int b = brow0 + i;
        const float v  = vel_t[b];
        const float hp = hprev[(size_t)b * H_DIM + j];
        const float pre = fmaf(v, gamma, 1.0f) + h2h[i];
        const float hn = OMA_F * hp + ALPHA_F * fmaxf(pre, 0.0f);
        acts_t[(size_t)b * H_DIM + j] = hn;
        hbf_out[(size_t)b * H_DIM + j] = f2bf(hn);
        if (outT) outT[(size_t)b * H_DIM + j] = hn;
    }
}

// ---------------------------------------------------------------------------
extern "C" void kernel_launch(void* const* d_in, const int* in_sizes, int n_in,
                              void* d_out, int out_size, void* d_ws, size_t ws_size,
                              hipStream_t stream) {
    const float* x       = (const float*)d_in[0];  // [T,B,IN]
    const float* hidden0 = (const float*)d_in[1];  // [B,H]
    const float* w_attr  = (const float*)d_in[2];  // [H,H]
    const float* w_in    = (const float*)d_in[3];  // [1,IN]

    float* acts = (float*)d_out;                               // [T,B,H]
    float* outT = acts + (size_t)T_STEPS * B_SZ * H_DIM;       // [B,H]

    unsigned char* ws = (unsigned char*)d_ws;
    unsigned short* Wt   = (unsigned short*)ws;                             // 8 MB
    unsigned short* hbf0 = (unsigned short*)(ws + ((size_t)8 << 20));       // 512 KB
    unsigned short* hbf1 = hbf0 + (size_t)B_SZ * H_DIM;                     // 512 KB
    float* vel = (float*)(ws + ((size_t)8 << 20) + (size_t)2 * B_SZ * H_DIM * 2); // 256 KB
    unsigned* bar = (unsigned*)(ws + ((size_t)8 << 20) + ((size_t)1 << 20) + (256 << 10)); // 4 KB

    hipMemsetAsync(bar, 0, 4096, stream);
    wt_kernel<<<dim3(32, 32), dim3(64, 4), 0, stream>>>(w_attr, Wt);
    vel_kernel<<<(T_STEPS * B_SZ + 255) / 256, 256, 0, stream>>>(x, w_in, vel);
    hbf_init_kernel<<<(B_SZ * H_DIM + 255) / 256, 256, 0, stream>>>(hidden0, hbf0);

    void* args[] = {(void*)&Wt, (void*)&hbf0, (void*)&hbf1, (void*)&vel,
                    (void*)&hidden0, (void*)&acts, (void*)&outT, (void*)&bar};
    hipError_t rc = hipLaunchCooperativeKernel(
        reinterpret_cast<void*>(ring_coop_kernel),
        dim3(256), dim3(256), args, 0, stream);

    if (rc != hipSuccess) {
        // fallback: per-step launches (round-1 path)
        for (int t = 0; t < T_STEPS; ++t) {
            const unsigned short* hin = (t & 1) ? hbf1 : hbf0;
            unsigned short* hout      = (t & 1) ? hbf0 : hbf1;
            const float* hprev = (t == 0) ? hidden0 : acts + (size_t)(t - 1) * B_SZ * H_DIM;
            step_kernel<<<256, 256, 0, stream>>>(
                Wt, hin, hout, vel + (size_t)t * B_SZ, hprev,
                acts + (size_t)t * B_SZ * H_DIM,
                (t == T_STEPS - 1) ? outT : nullptr);
        }
    }
}

// Round 4
// 9142.596 us; speedup vs baseline: 4.3734x; 2.8499x over previous
//
#include <hip/hip_runtime.h>

#define H_DIM   2048
#define N_HALF  1024
#define B_SZ    128
#define T_STEPS 512
#define IN_DIM  64
#define ALPHA_F 0.05f
#define OMA_F   0.95f   // 1 - ALPHA

typedef __bf16 bf16x8 __attribute__((ext_vector_type(8)));
typedef float  f32x4  __attribute__((ext_vector_type(4)));

// round-to-nearest-even f32 -> bf16 bits
__device__ __forceinline__ unsigned short f2bf(float f) {
    union { float f; unsigned int u; } v; v.f = f;
    unsigned int u = v.u;
    u += 0x7FFFu + ((u >> 16) & 1u);
    return (unsigned short)(u >> 16);
}

// coherent (agent-scope) 16B load of an A fragment: two 8B relaxed atomics.
// These bypass stale L1/L2 lines cross-XCD (same primitive as the barrier's
// gen-poll, validated in round 3).
__device__ __forceinline__ bf16x8 ldA(const unsigned long long* p) {
    union { unsigned long long u[2]; bf16x8 v; } c;
    c.u[0] = __hip_atomic_load(p,     __ATOMIC_RELAXED, __HIP_MEMORY_SCOPE_AGENT);
    c.u[1] = __hip_atomic_load(p + 1, __ATOMIC_RELAXED, __HIP_MEMORY_SCOPE_AGENT);
    return c.v;
}

// ---------------------------------------------------------------------------
// Wt[j][k] = bf16(W[k][j])  (transpose + convert, LDS-tiled 64x64)
// ---------------------------------------------------------------------------
__global__ void wt_kernel(const float* __restrict__ W, unsigned short* __restrict__ Wt) {
    __shared__ float tile[64][65];
    const int jb = blockIdx.x * 64;
    const int kb = blockIdx.y * 64;
    const int tx = threadIdx.x;   // 0..63
    const int ty = threadIdx.y;   // 0..3
    #pragma unroll
    for (int r = ty; r < 64; r += 4)
        tile[r][tx] = W[(size_t)(kb + r) * H_DIM + jb + tx];
    __syncthreads();
    #pragma unroll
    for (int r = ty; r < 64; r += 4)
        Wt[(size_t)(jb + r) * H_DIM + kb + tx] = f2bf(tile[tx][r]);
}

// ---------------------------------------------------------------------------
__global__ void vel_kernel(const float* __restrict__ x, const float* __restrict__ w_in,
                           float* __restrict__ vel) {
    const int tb = blockIdx.x * blockDim.x + threadIdx.x;
    if (tb >= T_STEPS * B_SZ) return;
    const float* xp = x + (size_t)tb * IN_DIM;
    float s = 0.f;
    #pragma unroll
    for (int i = 0; i < IN_DIM; i += 4) {
        float4 xv = *reinterpret_cast<const float4*>(xp + i);
        float4 wv = *reinterpret_cast<const float4*>(w_in + i);
        s += xv.x * wv.x + xv.y * wv.y + xv.z * wv.z + xv.w * wv.w;
    }
    vel[tb] = s;
}

// ---------------------------------------------------------------------------
__global__ void hbf_init_kernel(const float* __restrict__ h0, unsigned short* __restrict__ hbf) {
    const int i = blockIdx.x * blockDim.x + threadIdx.x;
    hbf[i] = f2bf(h0[i]);
}

// ---------------------------------------------------------------------------
// Two-level grid barrier (256 blocks = 16 groups x 16), NO cache-maintenance.
// Monotone counters (memset to 0 per launch -> deterministic).
// ---------------------------------------------------------------------------
__device__ __forceinline__ void ring_barrier(unsigned* bar, int t, int bid, int tid) {
    asm volatile("s_waitcnt vmcnt(0)" ::: "memory");  // h stores complete
    __syncthreads();                                   // all waves drained
    if (tid == 0) {
        unsigned* gcnt = bar + (bid >> 4) * 32;
        unsigned* rcnt = bar + 16 * 32;
        unsigned* gen  = bar + 16 * 32 + 32;
        unsigned old = __hip_atomic_fetch_add(gcnt, 1u, __ATOMIC_RELAXED,
                                              __HIP_MEMORY_SCOPE_AGENT);
        if (old == (unsigned)(t * 16 + 15)) {                 // last block of group
            unsigned r = __hip_atomic_fetch_add(rcnt, 1u, __ATOMIC_RELAXED,
                                                __HIP_MEMORY_SCOPE_AGENT);
            if (r == (unsigned)(t * 16 + 15)) {               // last group
                __hip_atomic_store(gen, (unsigned)(t + 1), __ATOMIC_RELAXED,
                                   __HIP_MEMORY_SCOPE_AGENT);
            }
        }
        while (__hip_atomic_load(gen, __ATOMIC_RELAXED, __HIP_MEMORY_SCOPE_AGENT)
               < (unsigned)(t + 1)) {
            __builtin_amdgcn_s_sleep(2);
        }
    }
    __syncthreads();
}

// ---------------------------------------------------------------------------
// Persistent kernel: all 512 steps in one launch.
// 256 blocks (1/CU) x 256 threads (4 waves). Block tile: 32 rows x 32 cols.
// B (Wt slice, 128 KB) in LDS forever, MFMA-fragment order (conflict-free
// ds_read_b128). h_prev f32 in registers. Cross-block h state via relaxed
// AGENT atomics only — zero fence/cache-op instructions in the loop.
// ---------------------------------------------------------------------------
__global__ __launch_bounds__(256, 1) void ring_coop_kernel(
        const unsigned short* __restrict__ Wt,
        unsigned short* __restrict__ hbf0,
        unsigned short* __restrict__ hbf1,
        const float* __restrict__ vel,
        const float* __restrict__ hidden0,
        float* __restrict__ acts,
        float* __restrict__ outT,
        unsigned* __restrict__ bar) {
    __shared__ __align__(16) unsigned char ldsB[131072];  // [ch][ks][q][col][16B]

    const int tid = threadIdx.x;
    const int bid = blockIdx.x;
    const int colg = bid & 63;          // 64 col-groups of 32
    const int rowg = bid >> 6;          // 4 row-groups of 32
    const int colbase = colg * 32;
    const int rowbase = rowg * 32;

    // ---- one-time: stage B slice into LDS in fragment order ----
    for (int c = tid; c < 8192; c += 256) {
        const int col = c & 15;
        const int q   = (c >> 4) & 3;
        const int ks  = (c >> 6) & 63;
        const int ch  = (c >> 12) & 1;
        const size_t src = (size_t)(colbase + ch * 16 + col) * H_DIM + ks * 32 + q * 8;
        *reinterpret_cast<uint4*>(ldsB + (size_t)c * 16) =
            *reinterpret_cast<const uint4*>(Wt + src);
    }
    __syncthreads();

    const int lane = tid & 63;
    const int w    = tid >> 6;              // 0..3
    const int rowhalf = w >> 1, colhalf = w & 1;
    const int wrow = rowbase + rowhalf * 16;
    const int wcol = colbase + colhalf * 16;
    const int r16  = lane & 15;
    const int q4   = lane >> 4;

    const unsigned char* Bp = ldsB + colhalf * 65536 + q4 * 256 + r16 * 16;
    const int j = wcol + r16;
    const float gamma = (j < N_HALF) ? -1.0f : 1.0f;
    const int brow0 = wrow + q4 * 4;

    // h_prev in registers: this thread owns (brow0..brow0+3, j)
    f32x4 hreg;
    #pragma unroll
    for (int i = 0; i < 4; ++i)
        hreg[i] = hidden0[(size_t)(brow0 + i) * H_DIM + j];

#define LOAD4(d0,d1,d2,d3,s)                         \
    d0 = ldA(Ap64 + ((size_t)(s)*4      )*2);        \
    d1 = ldA(Ap64 + ((size_t)(s)*4 +  64)*2);        \
    d2 = ldA(Ap64 + ((size_t)(s)*4 + 128)*2);        \
    d3 = ldA(Ap64 + ((size_t)(s)*4 + 192)*2);

#define STEP4(s, s0,s1,s2,s3) {                                                    \
    bf16x8 w0 = *reinterpret_cast<const bf16x8*>(Bp + (size_t)(s)      * 1024);    \
    bf16x8 w1 = *reinterpret_cast<const bf16x8*>(Bp + (size_t)((s)+16) * 1024);    \
    bf16x8 w2 = *reinterpret_cast<const bf16x8*>(Bp + (size_t)((s)+32) * 1024);    \
    bf16x8 w3 = *reinterpret_cast<const bf16x8*>(Bp + (size_t)((s)+48) * 1024);    \
    acc0 = __builtin_amdgcn_mfma_f32_16x16x32_bf16(s0, w0, acc0, 0, 0, 0);         \
    acc1 = __builtin_amdgcn_mfma_f32_16x16x32_bf16(s1, w1, acc1, 0, 0, 0);         \
    acc2 = __builtin_amdgcn_mfma_f32_16x16x32_bf16(s2, w2, acc2, 0, 0, 0);         \
    acc3 = __builtin_amdgcn_mfma_f32_16x16x32_bf16(s3, w3, acc3, 0, 0, 0); }

    for (int t = 0; t < T_STEPS; ++t) {
        const unsigned short* hin  = (t & 1) ? hbf1 : hbf0;
        unsigned short*       hout = (t & 1) ? hbf0 : hbf1;
        const float* vel_t  = vel + (size_t)t * B_SZ;

        // acts[t-1] stores: off the barrier critical path, overlap this step's GEMM
        if (t > 0) {
            float* acts_p = acts + (size_t)(t - 1) * B_SZ * H_DIM;
            #pragma unroll
            for (int i = 0; i < 4; ++i)
                acts_p[(size_t)(brow0 + i) * H_DIM + j] = hreg[i];
        }

        const unsigned long long* Ap64 = reinterpret_cast<const unsigned long long*>(
            hin + (size_t)(wrow + r16) * H_DIM + q4 * 8);

        f32x4 acc0 = {0.f,0.f,0.f,0.f}, acc1 = {0.f,0.f,0.f,0.f};
        f32x4 acc2 = {0.f,0.f,0.f,0.f}, acc3 = {0.f,0.f,0.f,0.f};

        bf16x8 xa0, xa1, xa2, xa3, xb0, xb1, xb2, xb3;
        LOAD4(xa0, xa1, xa2, xa3, 0)
        #pragma unroll
        for (int s = 0; s < 16; s += 2) {
            LOAD4(xb0, xb1, xb2, xb3, s + 1)
            STEP4(s, xa0, xa1, xa2, xa3)
            if (s + 2 < 16) { LOAD4(xa0, xa1, xa2, xa3, s + 2) }
            STEP4(s + 1, xb0, xb1, xb2, xb3)
        }
        f32x4 h2h = (acc0 + acc1) + (acc2 + acc3);

        #pragma unroll
        for (int i = 0; i < 4; ++i) {
            const int b = brow0 + i;
            const float v  = vel_t[b];
            const float pre = fmaf(v, gamma, 1.0f) + h2h[i];
            const float hn = OMA_F * hreg[i] + ALPHA_F * fmaxf(pre, 0.0f);
            hreg[i] = hn;
            __hip_atomic_store(hout + (size_t)b * H_DIM + j, f2bf(hn),
                               __ATOMIC_RELAXED, __HIP_MEMORY_SCOPE_AGENT);
        }

        ring_barrier(bar, t, bid, tid);
    }

    // final acts slice + hT (from registers; no cross-block data needed)
    float* acts_last = acts + (size_t)(T_STEPS - 1) * B_SZ * H_DIM;
    #pragma unroll
    for (int i = 0; i < 4; ++i) {
        const size_t off = (size_t)(brow0 + i) * H_DIM + j;
        acts_last[off] = hreg[i];
        outT[off]      = hreg[i];
    }
#undef LOAD4
#undef STEP4
}

// ---------------------------------------------------------------------------
// Fallback per-step kernel (round-1 proven path) if cooperative launch fails.
// ---------------------------------------------------------------------------
__global__ __launch_bounds__(256) void step_kernel(
        const unsigned short* __restrict__ Wt,
        const unsigned short* __restrict__ hbf_in,
        unsigned short* __restrict__ hbf_out,
        const float* __restrict__ vel_t,
        const float* __restrict__ hprev,
        float* __restrict__ acts_t,
        float* __restrict__ outT) {
    const int lane = threadIdx.x & 63;
    const int w    = threadIdx.x >> 6;
    const int bid  = blockIdx.x;
    const int mg   = bid >> 7;
    const int n    = bid & 127;
    const int base_b = mg * 64 + w * 16;
    const int base_j = n * 16;
    const int r16  = lane & 15;
    const int koff = (lane >> 4) * 8;

    const bf16x8* Ap = reinterpret_cast<const bf16x8*>(
        hbf_in + (size_t)(base_b + r16) * H_DIM + koff);
    const bf16x8* Bp = reinterpret_cast<const bf16x8*>(
        Wt + (size_t)(base_j + r16) * H_DIM + koff);

    f32x4 acc0 = {0.f, 0.f, 0.f, 0.f};
    f32x4 acc1 = {0.f, 0.f, 0.f, 0.f};
    #pragma unroll 4
    for (int kk = 0; kk < 32; ++kk) {
        bf16x8 a0 = Ap[kk * 4];
        bf16x8 b0 = Bp[kk * 4];
        bf16x8 a1 = Ap[kk * 4 + 128];
        bf16x8 b1 = Bp[kk * 4 + 128];
        acc0 = __builtin_amdgcn_mfma_f32_16x16x32_bf16(a0, b0, acc0, 0, 0, 0);
        acc1 = __builtin_amdgcn_mfma_f32_16x16x32_bf16(a1, b1, acc1, 0, 0, 0);
    }
    f32x4 h2h = acc0 + acc1;

    const int j = base_j + r16;
    const float gamma = (j < N_HALF) ? -1.0f : 1.0f;
    const int brow0 = base_b + (lane >> 4) * 4;
    #pragma unroll
    for (int i = 0; i < 4; ++i) {
        const int b = brow0 + i;
        const float v  = vel_t[b];
        const float hp = hprev[(size_t)b * H_DIM + j];
        const float pre = fmaf(v, gamma, 1.0f) + h2h[i];
        const float hn = OMA_F * hp + ALPHA_F * fmaxf(pre, 0.0f);
        acts_t[(size_t)b * H_DIM + j] = hn;
        hbf_out[(size_t)b * H_DIM + j] = f2bf(hn);
        if (outT) outT[(size_t)b * H_DIM + j] = hn;
    }
}

// ---------------------------------------------------------------------------
extern "C" void kernel_launch(void* const* d_in, const int* in_sizes, int n_in,
                              void* d_out, int out_size, void* d_ws, size_t ws_size,
                              hipStream_t stream) {
    const float* x       = (const float*)d_in[0];  // [T,B,IN]
    const float* hidden0 = (const float*)d_in[1];  // [B,H]
    const float* w_attr  = (const float*)d_in[2];  // [H,H]
    const float* w_in    = (const float*)d_in[3];  // [1,IN]

    float* acts = (float*)d_out;                               // [T,B,H]
    float* outT = acts + (size_t)T_STEPS * B_SZ * H_DIM;       // [B,H]

    unsigned char* ws = (unsigned char*)d_ws;
    unsigned short* Wt   = (unsigned short*)ws;                             // 8 MB
    unsigned short* hbf0 = (unsigned short*)(ws + ((size_t)8 << 20));       // 512 KB
    unsigned short* hbf1 = hbf0 + (size_t)B_SZ * H_DIM;                     // 512 KB
    float* vel = (float*)(ws + ((size_t)8 << 20) + (size_t)2 * B_SZ * H_DIM * 2); // 256 KB
    unsigned* bar = (unsigned*)(ws + ((size_t)8 << 20) + ((size_t)1 << 20) + (256 << 10)); // 4 KB

    hipMemsetAsync(bar, 0, 4096, stream);
    wt_kernel<<<dim3(32, 32), dim3(64, 4), 0, stream>>>(w_attr, Wt);
    vel_kernel<<<(T_STEPS * B_SZ + 255) / 256, 256, 0, stream>>>(x, w_in, vel);
    hbf_init_kernel<<<(B_SZ * H_DIM + 255) / 256, 256, 0, stream>>>(hidden0, hbf0);

    void* args[] = {(void*)&Wt, (void*)&hbf0, (void*)&hbf1, (void*)&vel,
                    (void*)&hidden0, (void*)&acts, (void*)&outT, (void*)&bar};
    hipError_t rc = hipLaunchCooperativeKernel(
        reinterpret_cast<void*>(ring_coop_kernel),
        dim3(256), dim3(256), args, 0, stream);

    if (rc != hipSuccess) {
        // fallback: per-step launches (round-1 path)
        for (int t = 0; t < T_STEPS; ++t) {
            const unsigned short* hin = (t & 1) ? hbf1 : hbf0;
            unsigned short* hout      = (t & 1) ? hbf0 : hbf1;
            const float* hprev = (t == 0) ? hidden0 : acts + (size_t)(t - 1) * B_SZ * H_DIM;
            step_kernel<<<256, 256, 0, stream>>>(
                Wt, hin, hout, vel + (size_t)t * B_SZ, hprev,
                acts + (size_t)t * B_SZ * H_DIM,
                (t == T_STEPS - 1) ? outT : nullptr);
        }
    }
}

// Round 5
// 8460.587 us; speedup vs baseline: 4.7260x; 1.0806x over previous
//
#include <hip/hip_runtime.h>

#define H_DIM   2048
#define N_HALF  1024
#define B_SZ    128
#define T_STEPS 512
#define IN_DIM  64
#define ALPHA_F 0.05f
#define OMA_F   0.95f   // 1 - ALPHA

typedef __bf16 bf16x8 __attribute__((ext_vector_type(8)));
typedef float  f32x4  __attribute__((ext_vector_type(4)));

// round-to-nearest-even f32 -> bf16 bits
__device__ __forceinline__ unsigned short f2bf(float f) {
    union { float f; unsigned int u; } v; v.f = f;
    unsigned int u = v.u;
    u += 0x7FFFu + ((u >> 16) & 1u);
    return (unsigned short)(u >> 16);
}

// ---------------------------------------------------------------------------
// Wt[j][k] = bf16(W[k][j])  (transpose + convert, LDS-tiled 64x64)
// ---------------------------------------------------------------------------
__global__ void wt_kernel(const float* __restrict__ W, unsigned short* __restrict__ Wt) {
    __shared__ float tile[64][65];
    const int jb = blockIdx.x * 64;
    const int kb = blockIdx.y * 64;
    const int tx = threadIdx.x;   // 0..63
    const int ty = threadIdx.y;   // 0..3
    #pragma unroll
    for (int r = ty; r < 64; r += 4)
        tile[r][tx] = W[(size_t)(kb + r) * H_DIM + jb + tx];
    __syncthreads();
    #pragma unroll
    for (int r = ty; r < 64; r += 4)
        Wt[(size_t)(jb + r) * H_DIM + kb + tx] = f2bf(tile[tx][r]);
}

// ---------------------------------------------------------------------------
__global__ void vel_kernel(const float* __restrict__ x, const float* __restrict__ w_in,
                           float* __restrict__ vel) {
    const int tb = blockIdx.x * blockDim.x + threadIdx.x;
    if (tb >= T_STEPS * B_SZ) return;
    const float* xp = x + (size_t)tb * IN_DIM;
    float s = 0.f;
    #pragma unroll
    for (int i = 0; i < IN_DIM; i += 4) {
        float4 xv = *reinterpret_cast<const float4*>(xp + i);
        float4 wv = *reinterpret_cast<const float4*>(w_in + i);
        s += xv.x * wv.x + xv.y * wv.y + xv.z * wv.z + xv.w * wv.w;
    }
    vel[tb] = s;
}

// ---------------------------------------------------------------------------
__global__ void hbf_init_kernel(const float* __restrict__ h0, unsigned short* __restrict__ hbf) {
    const int i = blockIdx.x * blockDim.x + threadIdx.x;
    hbf[i] = f2bf(h0[i]);
}

// ---------------------------------------------------------------------------
// Two-level grid barrier (256 blocks = 16 groups x 16), no cache-maintenance.
// Monotone counters (memset to 0 per launch -> deterministic).
// ---------------------------------------------------------------------------
__device__ __forceinline__ void ring_barrier(unsigned* bar, int t, int bid, int tid) {
    asm volatile("s_waitcnt vmcnt(0)" ::: "memory");  // h/acts stores complete
    __syncthreads();                                   // all waves drained
    if (tid == 0) {
        unsigned* gcnt = bar + (bid >> 4) * 32;
        unsigned* rcnt = bar + 16 * 32;
        unsigned* gen  = bar + 16 * 32 + 32;
        unsigned old = __hip_atomic_fetch_add(gcnt, 1u, __ATOMIC_RELAXED,
                                              __HIP_MEMORY_SCOPE_AGENT);
        if (old == (unsigned)(t * 16 + 15)) {                 // last block of group
            unsigned r = __hip_atomic_fetch_add(rcnt, 1u, __ATOMIC_RELAXED,
                                                __HIP_MEMORY_SCOPE_AGENT);
            if (r == (unsigned)(t * 16 + 15)) {               // last group
                __hip_atomic_store(gen, (unsigned)(t + 1), __ATOMIC_RELAXED,
                                   __HIP_MEMORY_SCOPE_AGENT);
            }
        }
        while (__hip_atomic_load(gen, __ATOMIC_RELAXED, __HIP_MEMORY_SCOPE_AGENT)
               < (unsigned)(t + 1)) {
            __builtin_amdgcn_s_sleep(1);
        }
    }
    __syncthreads();
    // Acquire: invalidate stale L1/L2 lines (h state written by other XCDs sits
    // in L3; our loop's stores all bypass L2, so nothing dirty can be lost).
    asm volatile("buffer_inv sc1\n\ts_waitcnt vmcnt(0)" ::: "memory");
}

// ---------------------------------------------------------------------------
// Persistent kernel: all 512 steps in one launch.
// 256 blocks (1/CU) x 256 threads (4 waves). Block tile: 32 rows x 32 cols.
// XCD swizzle: rowg = bid&3 -> all 32 blocks on an XCD read the SAME 32 A-rows
// (128 KB unique per XCD per step -> L2-cached after first touch).
// B (Wt slice, 128 KB) in LDS forever, MFMA-fragment order (conflict-free
// ds_read_b128). h_prev f32 in registers. All in-loop global stores are
// relaxed AGENT atomics (L2-bypass); A loads are plain cached loads made
// coherent by the barrier's buffer_inv.
// ---------------------------------------------------------------------------
__global__ __launch_bounds__(256, 1) void ring_coop_kernel(
        const unsigned short* __restrict__ Wt,
        unsigned short* __restrict__ hbf0,
        unsigned short* __restrict__ hbf1,
        const float* __restrict__ vel,
        const float* __restrict__ hidden0,
        float* __restrict__ acts,
        float* __restrict__ outT,
        unsigned* __restrict__ bar) {
    __shared__ __align__(16) unsigned char ldsB[131072];  // [ch][ks][q][col][16B]

    const int tid = threadIdx.x;
    const int bid = blockIdx.x;
    // XCD-aware swizzle (bid%8 = XCD round-robin): same-XCD blocks share rowg
    const int rowg = bid & 3;                         // 0..3
    const int colg = (bid >> 3) + ((bid & 4) << 3);   // 0..63
    const int colbase = colg * 32;
    const int rowbase = rowg * 32;

    // ---- one-time: stage B slice into LDS in fragment order ----
    for (int c = tid; c < 8192; c += 256) {
        const int col = c & 15;
        const int q   = (c >> 4) & 3;
        const int ks  = (c >> 6) & 63;
        const int ch  = (c >> 12) & 1;
        const size_t src = (size_t)(colbase + ch * 16 + col) * H_DIM + ks * 32 + q * 8;
        *reinterpret_cast<uint4*>(ldsB + (size_t)c * 16) =
            *reinterpret_cast<const uint4*>(Wt + src);
    }
    __syncthreads();

    const int lane = tid & 63;
    const int w    = tid >> 6;              // 0..3
    const int rowhalf = w >> 1, colhalf = w & 1;
    const int wrow = rowbase + rowhalf * 16;
    const int wcol = colbase + colhalf * 16;
    const int r16  = lane & 15;
    const int q4   = lane >> 4;

    const unsigned char* Bp = ldsB + colhalf * 65536 + q4 * 256 + r16 * 16;
    const int j = wcol + r16;
    const float gamma = (j < N_HALF) ? -1.0f : 1.0f;
    const int brow0 = wrow + q4 * 4;

    // h_prev in registers: this thread owns (brow0..brow0+3, j)
    f32x4 hreg;
    #pragma unroll
    for (int i = 0; i < 4; ++i)
        hreg[i] = hidden0[(size_t)(brow0 + i) * H_DIM + j];

// plain cached 16B loads of 4 A fragments (one per K-chain) for k-slice s
#define LOAD4(d0,d1,d2,d3,s)        \
    d0 = Ap[(s) * 4];               \
    d1 = Ap[(s) * 4 + 64];          \
    d2 = Ap[(s) * 4 + 128];         \
    d3 = Ap[(s) * 4 + 192];

#define STEP4(s, s0,s1,s2,s3) {                                                    \
    bf16x8 w0 = *reinterpret_cast<const bf16x8*>(Bp + (size_t)(s)      * 1024);    \
    bf16x8 w1 = *reinterpret_cast<const bf16x8*>(Bp + (size_t)((s)+16) * 1024);    \
    bf16x8 w2 = *reinterpret_cast<const bf16x8*>(Bp + (size_t)((s)+32) * 1024);    \
    bf16x8 w3 = *reinterpret_cast<const bf16x8*>(Bp + (size_t)((s)+48) * 1024);    \
    acc0 = __builtin_amdgcn_mfma_f32_16x16x32_bf16(s0, w0, acc0, 0, 0, 0);         \
    acc1 = __builtin_amdgcn_mfma_f32_16x16x32_bf16(s1, w1, acc1, 0, 0, 0);         \
    acc2 = __builtin_amdgcn_mfma_f32_16x16x32_bf16(s2, w2, acc2, 0, 0, 0);         \
    acc3 = __builtin_amdgcn_mfma_f32_16x16x32_bf16(s3, w3, acc3, 0, 0, 0); }

    for (int t = 0; t < T_STEPS; ++t) {
        const unsigned short* hin  = (t & 1) ? hbf1 : hbf0;
        unsigned short*       hout = (t & 1) ? hbf0 : hbf1;
        const float* vel_t  = vel + (size_t)t * B_SZ;

        // acts[t-1] stores: L2-bypassing (agent atomics) so buffer_inv can never
        // discard them; overlap this step's GEMM.
        if (t > 0) {
            float* acts_p = acts + (size_t)(t - 1) * B_SZ * H_DIM;
            #pragma unroll
            for (int i = 0; i < 4; ++i)
                __hip_atomic_store(acts_p + (size_t)(brow0 + i) * H_DIM + j, hreg[i],
                                   __ATOMIC_RELAXED, __HIP_MEMORY_SCOPE_AGENT);
        }

        // preload this step's vel values (post-inv L2 miss -> issue early)
        f32x4 vel4;
        #pragma unroll
        for (int i = 0; i < 4; ++i) vel4[i] = vel_t[brow0 + i];

        const bf16x8* Ap = reinterpret_cast<const bf16x8*>(
            hin + (size_t)(wrow + r16) * H_DIM + q4 * 8);

        f32x4 acc0 = {0.f,0.f,0.f,0.f}, acc1 = {0.f,0.f,0.f,0.f};
        f32x4 acc2 = {0.f,0.f,0.f,0.f}, acc3 = {0.f,0.f,0.f,0.f};

        // depth-4 software pipeline over the 16 k-slices
        bf16x8 pa0,pa1,pa2,pa3, pb0,pb1,pb2,pb3, pc0,pc1,pc2,pc3, pd0,pd1,pd2,pd3;
        LOAD4(pa0,pa1,pa2,pa3, 0)
        LOAD4(pb0,pb1,pb2,pb3, 1)
        LOAD4(pc0,pc1,pc2,pc3, 2)
        LOAD4(pd0,pd1,pd2,pd3, 3)
        #pragma unroll
        for (int r = 0; r < 16; r += 4) {
            STEP4(r + 0, pa0,pa1,pa2,pa3)
            if (r + 4 < 16) { LOAD4(pa0,pa1,pa2,pa3, r + 4) }
            STEP4(r + 1, pb0,pb1,pb2,pb3)
            if (r + 5 < 16) { LOAD4(pb0,pb1,pb2,pb3, r + 5) }
            STEP4(r + 2, pc0,pc1,pc2,pc3)
            if (r + 6 < 16) { LOAD4(pc0,pc1,pc2,pc3, r + 6) }
            STEP4(r + 3, pd0,pd1,pd2,pd3)
            if (r + 7 < 16) { LOAD4(pd0,pd1,pd2,pd3, r + 7) }
        }
        f32x4 h2h = (acc0 + acc1) + (acc2 + acc3);

        #pragma unroll
        for (int i = 0; i < 4; ++i) {
            const int b = brow0 + i;
            const float pre = fmaf(vel4[i], gamma, 1.0f) + h2h[i];
            const float hn = OMA_F * hreg[i] + ALPHA_F * fmaxf(pre, 0.0f);
            hreg[i] = hn;
            __hip_atomic_store(hout + (size_t)b * H_DIM + j, f2bf(hn),
                               __ATOMIC_RELAXED, __HIP_MEMORY_SCOPE_AGENT);
        }

        ring_barrier(bar, t, bid, tid);
    }

    // final acts slice + hT (from registers; plain stores, end-of-kernel flush)
    float* acts_last = acts + (size_t)(T_STEPS - 1) * B_SZ * H_DIM;
    #pragma unroll
    for (int i = 0; i < 4; ++i) {
        const size_t off = (size_t)(brow0 + i) * H_DIM + j;
        acts_last[off] = hreg[i];
        outT[off]      = hreg[i];
    }
#undef LOAD4
#undef STEP4
}

// ---------------------------------------------------------------------------
// Fallback per-step kernel (round-1 proven path) if cooperative launch fails.
// ---------------------------------------------------------------------------
__global__ __launch_bounds__(256) void step_kernel(
        const unsigned short* __restrict__ Wt,
        const unsigned short* __restrict__ hbf_in,
        unsigned short* __restrict__ hbf_out,
        const float* __restrict__ vel_t,
        const float* __restrict__ hprev,
        float* __restrict__ acts_t,
        float* __restrict__ outT) {
    const int lane = threadIdx.x & 63;
    const int w    = threadIdx.x >> 6;
    const int bid  = blockIdx.x;
    const int mg   = bid >> 7;
    const int n    = bid & 127;
    const int base_b = mg * 64 + w * 16;
    const int base_j = n * 16;
    const int r16  = lane & 15;
    const int koff = (lane >> 4) * 8;

    const bf16x8* Ap = reinterpret_cast<const bf16x8*>(
        hbf_in + (size_t)(base_b + r16) * H_DIM + koff);
    const bf16x8* Bp = reinterpret_cast<const bf16x8*>(
        Wt + (size_t)(base_j + r16) * H_DIM + koff);

    f32x4 acc0 = {0.f, 0.f, 0.f, 0.f};
    f32x4 acc1 = {0.f, 0.f, 0.f, 0.f};
    #pragma unroll 4
    for (int kk = 0; kk < 32; ++kk) {
        bf16x8 a0 = Ap[kk * 4];
        bf16x8 b0 = Bp[kk * 4];
        bf16x8 a1 = Ap[kk * 4 + 128];
        bf16x8 b1 = Bp[kk * 4 + 128];
        acc0 = __builtin_amdgcn_mfma_f32_16x16x32_bf16(a0, b0, acc0, 0, 0, 0);
        acc1 = __builtin_amdgcn_mfma_f32_16x16x32_bf16(a1, b1, acc1, 0, 0, 0);
    }
    f32x4 h2h = acc0 + acc1;

    const int j = base_j + r16;
    const float gamma = (j < N_HALF) ? -1.0f : 1.0f;
    const int brow0 = base_b + (lane >> 4) * 4;
    #pragma unroll
    for (int i = 0; i < 4; ++i) {
        const int b = brow0 + i;
        const float v  = vel_t[b];
        const float hp = hprev[(size_t)b * H_DIM + j];
        const float pre = fmaf(v, gamma, 1.0f) + h2h[i];
        const float hn = OMA_F * hp + ALPHA_F * fmaxf(pre, 0.0f);
        acts_t[(size_t)b * H_DIM + j] = hn;
        hbf_out[(size_t)b * H_DIM + j] = f2bf(hn);
        if (outT) outT[(size_t)b * H_DIM + j] = hn;
    }
}

// ---------------------------------------------------------------------------
extern "C" void kernel_launch(void* const* d_in, const int* in_sizes, int n_in,
                              void* d_out, int out_size, void* d_ws, size_t ws_size,
                              hipStream_t stream) {
    const float* x       = (const float*)d_in[0];  // [T,B,IN]
    const float* hidden0 = (const float*)d_in[1];  // [B,H]
    const float* w_attr  = (const float*)d_in[2];  // [H,H]
    const float* w_in    = (const float*)d_in[3];  // [1,IN]

    float* acts = (float*)d_out;                               // [T,B,H]
    float* outT = acts + (size_t)T_STEPS * B_SZ * H_DIM;       // [B,H]

    unsigned char* ws = (unsigned char*)d_ws;
    unsigned short* Wt   = (unsigned short*)ws;                             // 8 MB
    unsigned short* hbf0 = (unsigned short*)(ws + ((size_t)8 << 20));       // 512 KB
    unsigned short* hbf1 = hbf0 + (size_t)B_SZ * H_DIM;                     // 512 KB
    float* vel = (float*)(ws + ((size_t)8 << 20) + (size_t)2 * B_SZ * H_DIM * 2); // 256 KB
    unsigned* bar = (unsigned*)(ws + ((size_t)8 << 20) + ((size_t)1 << 20) + (256 << 10)); // 4 KB

    hipMemsetAsync(bar, 0, 4096, stream);
    wt_kernel<<<dim3(32, 32), dim3(64, 4), 0, stream>>>(w_attr, Wt);
    vel_kernel<<<(T_STEPS * B_SZ + 255) / 256, 256, 0, stream>>>(x, w_in, vel);
    hbf_init_kernel<<<(B_SZ * H_DIM + 255) / 256, 256, 0, stream>>>(hidden0, hbf0);

    void* args[] = {(void*)&Wt, (void*)&hbf0, (void*)&hbf1, (void*)&vel,
                    (void*)&hidden0, (void*)&acts, (void*)&outT, (void*)&bar};
    hipError_t rc = hipLaunchCooperativeKernel(
        reinterpret_cast<void*>(ring_coop_kernel),
        dim3(256), dim3(256), args, 0, stream);

    if (rc != hipSuccess) {
        // fallback: per-step launches (round-1 path)
        for (int t = 0; t < T_STEPS; ++t) {
            const unsigned short* hin = (t & 1) ? hbf1 : hbf0;
            unsigned short* hout      = (t & 1) ? hbf0 : hbf1;
            const float* hprev = (t == 0) ? hidden0 : acts + (size_t)(t - 1) * B_SZ * H_DIM;
            step_kernel<<<256, 256, 0, stream>>>(
                Wt, hin, hout, vel + (size_t)t * B_SZ, hprev,
                acts + (size_t)t * B_SZ * H_DIM,
                (t == T_STEPS - 1) ? outT : nullptr);
        }
    }
}